// Round 1
// baseline (1106.866 us; speedup 1.0000x reference)
//
#include <hip/hip_runtime.h>
#include <hip/hip_bf16.h>

#define B_   2
#define N_   384
#define DIM_ 256
#define H_   4
#define DH_  64
#define PD_  128
#define ED_  16

// ---------- helpers ----------
__device__ __forceinline__ float bf2f(unsigned short u) {
    return __uint_as_float(((unsigned int)u) << 16);
}
__device__ __forceinline__ unsigned short f2bf(float f) {
    unsigned int x = __float_as_uint(f);
    unsigned int r = (x + 0x7fffu + ((x >> 16) & 1u)) >> 16;
    return (unsigned short)r;
}
__device__ __forceinline__ float silu_(float x) { return x / (1.0f + __expf(-x)); }
__device__ __forceinline__ float gelu_(float x) {
    return 0.5f * x * (1.0f + erff(x * 0.70710678118654752f));
}

// full-block reduction (returns result to all threads). red must hold >= nwaves floats.
__device__ __forceinline__ float block_reduce(float v, bool ismax, float* red, int nwaves) {
    #pragma unroll
    for (int o = 32; o > 0; o >>= 1) {
        float w = __shfl_xor(v, o, 64);
        v = ismax ? fmaxf(v, w) : (v + w);
    }
    __syncthreads();
    if ((threadIdx.x & 63) == 0) red[threadIdx.x >> 6] = v;
    __syncthreads();
    float r = red[0];
    for (int w = 1; w < nwaves; w++) r = ismax ? fmaxf(r, red[w]) : (r + red[w]);
    return r;
}

// team (32 lanes) LayerNorm over 128 channels (4 per lane) + SiLU
__device__ __forceinline__ void team_ln_silu(float v[4], const float g[4], const float be[4]) {
    float s = v[0] + v[1] + v[2] + v[3];
    #pragma unroll
    for (int o = 16; o > 0; o >>= 1) s += __shfl_xor(s, o, 32);
    float mean = s * (1.0f / 128.0f);
    float d0 = v[0] - mean, d1 = v[1] - mean, d2 = v[2] - mean, d3 = v[3] - mean;
    float q = d0 * d0 + d1 * d1 + d2 * d2 + d3 * d3;
    #pragma unroll
    for (int o = 16; o > 0; o >>= 1) q += __shfl_xor(q, o, 32);
    float inv = rsqrtf(q * (1.0f / 128.0f) + 1e-5f);
    v[0] = silu_(d0 * inv * g[0] + be[0]);
    v[1] = silu_(d1 * inv * g[1] + be[1]);
    v[2] = silu_(d2 * inv * g[2] + be[2]);
    v[3] = silu_(d3 * inv * g[3] + be[3]);
}

// ---------- K1: LayerNorm + QKV + gates ----------
__global__ __launch_bounds__(256) void eq_k1(
    const float* __restrict__ feats, const float* __restrict__ gamma,
    const float* __restrict__ w_qkv, const float* __restrict__ w_gate,
    const float* __restrict__ b_gate,
    float* __restrict__ q, float* __restrict__ kT, float* __restrict__ v,
    float* __restrict__ og, float* __restrict__ rg) {
    int row = blockIdx.x;           // b*N + n
    int b = row / N_, n = row - b * N_;
    int t = threadIdx.x;
    __shared__ float xs[DIM_];
    __shared__ float red[4];
    float f = feats[(long)row * DIM_ + t];
    float mean = block_reduce(f, false, red, 4) * (1.0f / DIM_);
    float d = f - mean;
    float var = block_reduce(d * d, false, red, 4) * (1.0f / DIM_);
    float x = d * rsqrtf(var + 1e-5f) * gamma[t];
    xs[t] = x;
    __syncthreads();
    float a0 = 0, a1 = 0, a2 = 0;
    for (int c = 0; c < DIM_; c++) {
        float xc = xs[c];
        const float* wr = w_qkv + (long)c * 768;
        a0 += xc * wr[t];
        a1 += xc * wr[t + 256];
        a2 += xc * wr[t + 512];
    }
    int h = t >> 6, dd = t & 63;
    q[((b * H_ + h) * N_ + n) * DH_ + dd]  = a0 * 0.125f;      // dh^-0.5 pre-applied
    kT[((b * H_ + h) * DH_ + dd) * N_ + n] = a1;               // transposed for coalesced K3
    v[((b * H_ + h) * N_ + n) * DH_ + dd]  = a2;
    if (t < 8) {
        float acc = b_gate[t];
        for (int c = 0; c < DIM_; c++) acc += xs[c] * w_gate[c * 8 + t];
        float g = 1.0f / (1.0f + __expf(-acc));
        if (t < 4) og[(b * H_ + t) * N_ + n] = g;
        else       rg[(b * H_ + (t - 4)) * N_ + n] = g;
    }
}

// ---------- K2: per-pair position-bias MLP (the hot kernel) ----------
// 256 threads = 8 teams of 32; each team handles one (b,i,j) pair, 4 channels/lane.
// Dynamic LDS: W1 bf16 (32KB) + W2 bf16 (32KB) + h-buffer 8x128 f32 (4KB) = 69632 B.
__global__ __launch_bounds__(256) void eq_k2(
    const float* __restrict__ coors,
    const float* __restrict__ w0, const float* __restrict__ b0,
    const float* __restrict__ g0, const float* __restrict__ be0,
    const float* __restrict__ W1g, const float* __restrict__ b1,
    const float* __restrict__ g1, const float* __restrict__ be1,
    const float* __restrict__ W2g, const float* __restrict__ b2,
    const float* __restrict__ g2, const float* __restrict__ be2,
    const float* __restrict__ wqk, const float* __restrict__ bqk,
    unsigned short* __restrict__ pout, float* __restrict__ qkpos) {
    extern __shared__ char smem[];
    unsigned short* W1 = (unsigned short*)smem;
    unsigned short* W2 = W1 + PD_ * PD_;
    float* hb = (float*)(smem + 2 * PD_ * PD_ * sizeof(unsigned short));
    const int t = threadIdx.x;
    for (int idx = t; idx < PD_ * PD_; idx += 256) {
        W1[idx] = f2bf(W1g[idx]);
        W2[idx] = f2bf(W2g[idx]);
    }
    const int team = t >> 5, lane = t & 31, c4 = lane << 2;
    // hoist per-channel params to registers
    float w0r[4], b0r[4], g0r[4], be0r[4], b1r[4], g1r[4], be1r[4], b2r[4], g2r[4], be2r[4];
    float wqr[4][4];
    #pragma unroll
    for (int k = 0; k < 4; k++) {
        int c = c4 + k;
        w0r[k] = w0[c];  b0r[k] = b0[c];  g0r[k] = g0[c];  be0r[k] = be0[c];
        b1r[k] = b1[c];  g1r[k] = g1[c];  be1r[k] = be1[c];
        b2r[k] = b2[c];  g2r[k] = g2[c];  be2r[k] = be2[c];
        #pragma unroll
        for (int h = 0; h < 4; h++) wqr[k][h] = wqk[c * 4 + h];
    }
    float bq0 = bqk[0], bq1 = bqk[1], bq2 = bqk[2], bq3 = bqk[3];
    float* hrow = hb + team * PD_;
    __syncthreads();

    const int TOT = B_ * N_ * N_;          // 294912 = 1024 blocks * 36 iters * 8 pairs
    for (int base = blockIdx.x * 8; base < TOT; base += gridDim.x * 8) {
        int P = base + team;
        int b = P / (N_ * N_);
        int r = P - b * (N_ * N_);
        int i = r / N_, j = r - i * N_;
        float dx = coors[(b * N_ + i) * 3 + 0] - coors[(b * N_ + j) * 3 + 0];
        float dy = coors[(b * N_ + i) * 3 + 1] - coors[(b * N_ + j) * 3 + 1];
        float dz = coors[(b * N_ + i) * 3 + 2] - coors[(b * N_ + j) * 3 + 2];
        float dist = sqrtf(dx * dx + dy * dy + dz * dz);

        float vv[4];
        #pragma unroll
        for (int k = 0; k < 4; k++) vv[k] = dist * w0r[k] + b0r[k];
        team_ln_silu(vv, g0r, be0r);
        *(float4*)(hrow + c4) = make_float4(vv[0], vv[1], vv[2], vv[3]);
        __syncthreads();

        float acc[4] = {b1r[0], b1r[1], b1r[2], b1r[3]};
        #pragma unroll 4
        for (int k = 0; k < PD_; k++) {
            float hk = hrow[k];
            ushort4 w = *(const ushort4*)(W1 + k * PD_ + c4);
            acc[0] += hk * bf2f(w.x); acc[1] += hk * bf2f(w.y);
            acc[2] += hk * bf2f(w.z); acc[3] += hk * bf2f(w.w);
        }
        team_ln_silu(acc, g1r, be1r);
        __syncthreads();
        *(float4*)(hrow + c4) = make_float4(acc[0], acc[1], acc[2], acc[3]);
        __syncthreads();

        float pc[4] = {b2r[0], b2r[1], b2r[2], b2r[3]};
        #pragma unroll 4
        for (int k = 0; k < PD_; k++) {
            float hk = hrow[k];
            ushort4 w = *(const ushort4*)(W2 + k * PD_ + c4);
            pc[0] += hk * bf2f(w.x); pc[1] += hk * bf2f(w.y);
            pc[2] += hk * bf2f(w.z); pc[3] += hk * bf2f(w.w);
        }
        team_ln_silu(pc, g2r, be2r);

        ushort4 up;
        up.x = f2bf(pc[0]); up.y = f2bf(pc[1]); up.z = f2bf(pc[2]); up.w = f2bf(pc[3]);
        *(ushort4*)(pout + (long)P * PD_ + c4) = up;

        float qp0 = pc[0] * wqr[0][0] + pc[1] * wqr[1][0] + pc[2] * wqr[2][0] + pc[3] * wqr[3][0];
        float qp1 = pc[0] * wqr[0][1] + pc[1] * wqr[1][1] + pc[2] * wqr[2][1] + pc[3] * wqr[3][1];
        float qp2 = pc[0] * wqr[0][2] + pc[1] * wqr[1][2] + pc[2] * wqr[2][2] + pc[3] * wqr[3][2];
        float qp3 = pc[0] * wqr[0][3] + pc[1] * wqr[1][3] + pc[2] * wqr[2][3] + pc[3] * wqr[3][3];
        #pragma unroll
        for (int o = 16; o > 0; o >>= 1) {
            qp0 += __shfl_xor(qp0, o, 32); qp1 += __shfl_xor(qp1, o, 32);
            qp2 += __shfl_xor(qp2, o, 32); qp3 += __shfl_xor(qp3, o, 32);
        }
        if (lane == 0) {
            float* qo = qkpos + (long)P * 4;
            qo[0] = qp0 + bq0; qo[1] = qp1 + bq1; qo[2] = qp2 + bq2; qo[3] = qp3 + bq3;
        }
        __syncthreads();
    }
}

// ---------- K3: qk scores + edge MLP -> cmi / coor_pre / rel_sign ----------
__global__ __launch_bounds__(384) void eq_k3(
    const float* __restrict__ q, const float* __restrict__ kT,
    const float* __restrict__ edges, const float* __restrict__ qkpos,
    const float* __restrict__ w_e1, const float* __restrict__ w_e2,
    const float* __restrict__ w_c, const float* __restrict__ w_cg,
    const float* __restrict__ b_cg,
    float* __restrict__ score, float* __restrict__ coorpre, float* __restrict__ relsign) {
    int row = blockIdx.x;           // b*N + i
    int b = row / N_, i = row - b * N_;
    int j = threadIdx.x;
    __shared__ float qs[H_ * DH_];
    __shared__ float we1[20 * 40];
    __shared__ float we2[40 * 4];
    __shared__ float wcs[16], wcgs[16], bcgs[4];
    if (j < 256) qs[j] = q[((b * H_ + (j >> 6)) * N_ + i) * DH_ + (j & 63)];
    for (int idx = j; idx < 800; idx += 384) we1[idx] = w_e1[idx];
    if (j < 160) we2[j] = w_e2[j];
    if (j < 16) { wcs[j] = w_c[j]; wcgs[j] = w_cg[j]; }
    if (j < 4) bcgs[j] = b_cg[j];
    __syncthreads();

    long pair = ((long)(b * N_ + i)) * N_ + j;
    float in20[20];
    #pragma unroll
    for (int h = 0; h < H_; h++) {
        float acc = 0;
        const float* kp = kT + ((long)(b * H_ + h) * DH_) * N_ + j;
        #pragma unroll 8
        for (int d = 0; d < DH_; d++) acc += qs[h * DH_ + d] * kp[(long)d * N_];
        in20[h] = acc + qkpos[pair * 4 + h];
    }
    const float4* ep = (const float4*)(edges + pair * ED_);
    float4 e0 = ep[0], e1 = ep[1], e2 = ep[2], e3 = ep[3];
    in20[4] = e0.x;  in20[5] = e0.y;  in20[6] = e0.z;  in20[7] = e0.w;
    in20[8] = e1.x;  in20[9] = e1.y;  in20[10] = e1.z; in20[11] = e1.w;
    in20[12] = e2.x; in20[13] = e2.y; in20[14] = e2.z; in20[15] = e2.w;
    in20[16] = e3.x; in20[17] = e3.y; in20[18] = e3.z; in20[19] = e3.w;

    float c0 = 0, c1 = 0, c2 = 0, c3 = 0;
    for (int o = 0; o < 40; o++) {
        float a = 0;
        #pragma unroll
        for (int c = 0; c < 20; c++) a += in20[c] * we1[c * 40 + o];
        float gg = gelu_(a);
        c0 += gg * we2[o * 4 + 0]; c1 += gg * we2[o * 4 + 1];
        c2 += gg * we2[o * 4 + 2]; c3 += gg * we2[o * 4 + 3];
    }
    float cmi[4] = {c0, c1, c2, c3};
    float gc[4];
    #pragma unroll
    for (int h = 0; h < 4; h++) gc[h] = gelu_(cmi[h]);
    #pragma unroll
    for (int h = 0; h < 4; h++) {
        long idx = (((long)(b * H_ + h) * N_ + i)) * N_ + j;
        score[idx] = cmi[h];
        coorpre[idx] = gc[0] * wcs[0 * 4 + h] + gc[1] * wcs[1 * 4 + h]
                     + gc[2] * wcs[2 * 4 + h] + gc[3] * wcs[3 * 4 + h];
        relsign[idx] = cmi[0] * wcgs[0 * 4 + h] + cmi[1] * wcgs[1 * 4 + h]
                     + cmi[2] * wcgs[2 * 4 + h] + cmi[3] * wcgs[3 * 4 + h] + bcgs[h];
    }
}

// ---------- K4a: softmax over j + talking heads ----------
__global__ __launch_bounds__(384) void eq_k4a(
    const float* __restrict__ score, const float* __restrict__ w_th,
    float* __restrict__ attn) {
    int row = blockIdx.x;
    int b = row / N_, i = row - b * N_;
    int j = threadIdx.x;
    __shared__ float red[8];
    float s[4], e[4], il[4];
    #pragma unroll
    for (int g = 0; g < 4; g++)
        s[g] = score[(((long)(b * H_ + g) * N_ + i)) * N_ + j];
    for (int g = 0; g < 4; g++) {
        float m = block_reduce(s[g], true, red, 6);
        e[g] = __expf(s[g] - m);
        float l = block_reduce(e[g], false, red, 6);
        il[g] = 1.0f / l;
    }
    #pragma unroll
    for (int h = 0; h < 4; h++) {
        float o = 0;
        #pragma unroll
        for (int g = 0; g < 4; g++) o += w_th[h * 4 + g] * e[g] * il[g];
        attn[(((long)(b * H_ + h) * N_ + i)) * N_ + j] = o;
    }
}

// ---------- K4b: coordinate branch -> out1 ----------
__global__ __launch_bounds__(384) void eq_k4b(
    const float* __restrict__ coorpre, const float* __restrict__ relsign,
    const float* __restrict__ coors, const float* __restrict__ rg,
    const float* __restrict__ cscale, const float* __restrict__ ccomb,
    float* __restrict__ out1) {
    int row = blockIdx.x;
    int b = row / N_, i = row - b * N_;
    int j = threadIdx.x;
    __shared__ float red[8];
    float cw[4], rs[4];
    #pragma unroll
    for (int h = 0; h < 4; h++) {
        long idx = (((long)(b * H_ + h) * N_ + i)) * N_ + j;
        cw[h] = coorpre[idx];
        rs[h] = relsign[idx];
    }
    float dx = coors[(b * N_ + i) * 3 + 0] - coors[(b * N_ + j) * 3 + 0];
    float dy = coors[(b * N_ + i) * 3 + 1] - coors[(b * N_ + j) * 3 + 1];
    float dz = coors[(b * N_ + i) * 3 + 2] - coors[(b * N_ + j) * 3 + 2];
    float nrm = sqrtf(dx * dx + dy * dy + dz * dz);
    float sc = cscale[0] / fmaxf(nrm, 1e-8f);
    float rx = dx * sc, ry = dy * sc, rz = dz * sc;
    float ox = 0, oy = 0, oz = 0;
    for (int h = 0; h < 4; h++) {
        float m = block_reduce(cw[h], true, red, 6);
        float e = __expf(cw[h] - m);
        float l = block_reduce(e, false, red, 6);
        float w = e / l * rs[h];
        float sx = block_reduce(w * rx, false, red, 6);
        float sy = block_reduce(w * ry, false, red, 6);
        float sz = block_reduce(w * rz, false, red, 6);
        float f = ccomb[h] * rg[(b * H_ + h) * N_ + i];
        ox += f * sx; oy += f * sy; oz += f * sz;
    }
    if (j == 0) {
        out1[(b * N_ + i) * 3 + 0] = ox;
        out1[(b * N_ + i) * 3 + 1] = oy;
        out1[(b * N_ + i) * 3 + 2] = oz;
    }
}

// ---------- K5a: ap[b,h,i,c] = sum_j attn * p ----------
__global__ __launch_bounds__(128) void eq_k5a(
    const float* __restrict__ attn, const unsigned short* __restrict__ p,
    float* __restrict__ ap) {
    int row = blockIdx.x;           // b*N + i
    int b = row / N_, i = row - b * N_;
    int t = threadIdx.x;            // channel c
    __shared__ float arow[4 * N_];
    for (int idx = t; idx < 4 * N_; idx += 128) {
        int g = idx / N_, j = idx - g * N_;
        arow[idx] = attn[(((long)(b * H_ + g) * N_ + i)) * N_ + j];
    }
    __syncthreads();
    float a0 = 0, a1 = 0, a2 = 0, a3 = 0;
    const unsigned short* pp = p + (long)row * N_ * PD_ + t;
    #pragma unroll 4
    for (int j = 0; j < N_; j++) {
        float pv = bf2f(pp[(long)j * PD_]);
        a0 += arow[j] * pv;
        a1 += arow[N_ + j] * pv;
        a2 += arow[2 * N_ + j] * pv;
        a3 += arow[3 * N_ + j] * pv;
    }
    ap[(((long)(b * H_ + 0) * N_ + i)) * PD_ + t] = a0;
    ap[(((long)(b * H_ + 1) * N_ + i)) * PD_ + t] = a1;
    ap[(((long)(b * H_ + 2) * N_ + i)) * PD_ + t] = a2;
    ap[(((long)(b * H_ + 3) * N_ + i)) * PD_ + t] = a3;
}

// ---------- K5b: node_out = attn@v + ap@w_vpos + S_h*b_vpos, gated ----------
__global__ __launch_bounds__(64) void eq_k5b(
    const float* __restrict__ attn, const float* __restrict__ v,
    const float* __restrict__ ap, const float* __restrict__ w_vpos,
    const float* __restrict__ b_vpos, const float* __restrict__ w_th,
    const float* __restrict__ og, float* __restrict__ node) {
    int blk = blockIdx.x;           // (b*H+h)*N + i
    int bh = blk / N_, i = blk - bh * N_;
    int b = bh / H_, h = bh - b * H_;
    int d = threadIdx.x;
    __shared__ float arow[N_];
    __shared__ float aprow[PD_];
    for (int idx = d; idx < N_; idx += 64) arow[idx] = attn[(long)blk * N_ + idx];
    for (int idx = d; idx < PD_; idx += 64) aprow[idx] = ap[(long)blk * PD_ + idx];
    __syncthreads();
    float acc = 0;
    const float* vp = v + ((long)(b * H_ + h) * N_) * DH_ + d;
    #pragma unroll 8
    for (int j = 0; j < N_; j++) acc += arow[j] * vp[(long)j * DH_];
    float accp = 0;
    const float* wv = w_vpos + h * DH_ + d;
    #pragma unroll 8
    for (int c = 0; c < PD_; c++) accp += aprow[c] * wv[(long)c * (H_ * DH_)];
    float Sh = w_th[h * 4 + 0] + w_th[h * 4 + 1] + w_th[h * 4 + 2] + w_th[h * 4 + 3];
    float out = (acc + accp + Sh * b_vpos[h * DH_ + d]) * og[(b * H_ + h) * N_ + i];
    node[((long)(b * N_ + i) * H_ + h) * DH_ + d] = out;
}

// ---------- K6: final projection ----------
__global__ __launch_bounds__(256) void eq_k6(
    const float* __restrict__ node, const float* __restrict__ w_out,
    const float* __restrict__ b_out, float* __restrict__ out0) {
    int row = blockIdx.x;           // b*N + i
    int t = threadIdx.x;
    __shared__ float xs[256];
    xs[t] = node[(long)row * 256 + t];
    __syncthreads();
    float acc = b_out[t];
    for (int c = 0; c < 256; c++) acc += xs[c] * w_out[(long)c * 256 + t];
    out0[(long)row * 256 + t] = acc;
}

extern "C" void kernel_launch(void* const* d_in, const int* in_sizes, int n_in,
                              void* d_out, int out_size, void* d_ws, size_t ws_size,
                              hipStream_t stream) {
    (void)in_sizes; (void)n_in; (void)out_size; (void)ws_size;
    const float* feats   = (const float*)d_in[0];
    const float* coors   = (const float*)d_in[1];
    const float* edges   = (const float*)d_in[2];
    const float* gamma   = (const float*)d_in[3];
    const float* w_qkv   = (const float*)d_in[4];
    const float* w_gate  = (const float*)d_in[5];
    const float* b_gate  = (const float*)d_in[6];
    const float* w_th    = (const float*)d_in[7];
    const float* w_e1    = (const float*)d_in[8];
    const float* w_e2    = (const float*)d_in[9];
    const float* w_c     = (const float*)d_in[10];
    const float* w_cg    = (const float*)d_in[11];
    const float* b_cg    = (const float*)d_in[12];
    const float* cscale  = (const float*)d_in[13];
    const float* ccomb   = (const float*)d_in[14];
    const float* pb_w0   = (const float*)d_in[15];
    const float* pb_b0   = (const float*)d_in[16];
    const float* pb_g0   = (const float*)d_in[17];
    const float* pb_be0  = (const float*)d_in[18];
    const float* pb_w1   = (const float*)d_in[19];
    const float* pb_b1   = (const float*)d_in[20];
    const float* pb_g1   = (const float*)d_in[21];
    const float* pb_be1  = (const float*)d_in[22];
    const float* pb_w2   = (const float*)d_in[23];
    const float* pb_b2   = (const float*)d_in[24];
    const float* pb_g2   = (const float*)d_in[25];
    const float* pb_be2  = (const float*)d_in[26];
    const float* w_qkpos = (const float*)d_in[27];
    const float* b_qkpos = (const float*)d_in[28];
    const float* w_vpos  = (const float*)d_in[29];
    const float* b_vpos  = (const float*)d_in[30];
    const float* w_out   = (const float*)d_in[31];
    const float* b_out   = (const float*)d_in[32];

    // workspace carve (floats)
    float* wsf    = (float*)d_ws;
    float* q      = wsf;                    // 196608
    float* kT     = q      + 196608;        // 196608
    float* v      = kT     + 196608;        // 196608
    float* og     = v      + 196608;        // 3072
    float* rg     = og     + 3072;          // 3072
    float* qkpos  = rg     + 3072;          // 1179648 (b,i,j,h)
    float* score  = qkpos  + 1179648;       // 1179648 (b,h,i,j)
    float* coorpre= score  + 1179648;       // 1179648
    float* relsign= coorpre+ 1179648;       // 1179648
    float* attn   = relsign+ 1179648;       // 1179648
    float* ap     = attn   + 1179648;       // 393216
    float* node   = ap     + 393216;        // 196608
    unsigned short* pbuf = (unsigned short*)(node + 196608);  // 37748736 bf16

    float* out0 = (float*)d_out;
    float* out1 = out0 + (long)B_ * N_ * DIM_;

    const int K2_LDS = 2 * PD_ * PD_ * (int)sizeof(unsigned short) + 8 * PD_ * (int)sizeof(float); // 69632
    hipFuncSetAttribute((const void*)eq_k2, hipFuncAttributeMaxDynamicSharedMemorySize, K2_LDS);

    eq_k1<<<B_ * N_, 256, 0, stream>>>(feats, gamma, w_qkv, w_gate, b_gate, q, kT, v, og, rg);
    eq_k2<<<1024, 256, K2_LDS, stream>>>(coors, pb_w0, pb_b0, pb_g0, pb_be0,
                                         pb_w1, pb_b1, pb_g1, pb_be1,
                                         pb_w2, pb_b2, pb_g2, pb_be2,
                                         w_qkpos, b_qkpos, pbuf, qkpos);
    eq_k3<<<B_ * N_, 384, 0, stream>>>(q, kT, edges, qkpos, w_e1, w_e2, w_c, w_cg, b_cg,
                                       score, coorpre, relsign);
    eq_k4a<<<B_ * N_, 384, 0, stream>>>(score, w_th, attn);
    eq_k4b<<<B_ * N_, 384, 0, stream>>>(coorpre, relsign, coors, rg, cscale, ccomb, out1);
    eq_k5a<<<B_ * N_, 128, 0, stream>>>(attn, pbuf, ap);
    eq_k5b<<<B_ * H_ * N_, 64, 0, stream>>>(attn, v, ap, w_vpos, b_vpos, w_th, og, node);
    eq_k6<<<B_ * N_, 256, 0, stream>>>(node, w_out, b_out, out0);
}

// Round 2
// 408.248 us; speedup vs baseline: 2.7113x; 2.7113x over previous
//
#include <hip/hip_runtime.h>
#include <hip/hip_bf16.h>

#define B_   2
#define N_   384
#define DIM_ 256
#define H_   4
#define DH_  64
#define PD_  128
#define ED_  16

typedef _Float16 v8h __attribute__((ext_vector_type(8)));
typedef float    v4f __attribute__((ext_vector_type(4)));

// ---------- helpers ----------
__device__ __forceinline__ float silu_(float x) { return x / (1.0f + __expf(-x)); }
__device__ __forceinline__ float gelu_(float x) {
    return 0.5f * x * (1.0f + erff(x * 0.70710678118654752f));
}

// full-block reduction (returns result to all threads). red must hold >= nwaves floats.
__device__ __forceinline__ float block_reduce(float v, bool ismax, float* red, int nwaves) {
    #pragma unroll
    for (int o = 32; o > 0; o >>= 1) {
        float w = __shfl_xor(v, o, 64);
        v = ismax ? fmaxf(v, w) : (v + w);
    }
    __syncthreads();
    if ((threadIdx.x & 63) == 0) red[threadIdx.x >> 6] = v;
    __syncthreads();
    float r = red[0];
    for (int w = 1; w < nwaves; w++) r = ismax ? fmaxf(r, red[w]) : (r + red[w]);
    return r;
}

// ---------- K1: LayerNorm + QKV + gates ----------
__global__ __launch_bounds__(256) void eq_k1(
    const float* __restrict__ feats, const float* __restrict__ gamma,
    const float* __restrict__ w_qkv, const float* __restrict__ w_gate,
    const float* __restrict__ b_gate,
    float* __restrict__ q, float* __restrict__ kT, float* __restrict__ v,
    float* __restrict__ og, float* __restrict__ rg) {
    int row = blockIdx.x;           // b*N + n
    int b = row / N_, n = row - b * N_;
    int t = threadIdx.x;
    __shared__ float xs[DIM_];
    __shared__ float red[4];
    float f = feats[(long)row * DIM_ + t];
    float mean = block_reduce(f, false, red, 4) * (1.0f / DIM_);
    float d = f - mean;
    float var = block_reduce(d * d, false, red, 4) * (1.0f / DIM_);
    float x = d * rsqrtf(var + 1e-5f) * gamma[t];
    xs[t] = x;
    __syncthreads();
    float a0 = 0, a1 = 0, a2 = 0;
    for (int c = 0; c < DIM_; c++) {
        float xc = xs[c];
        const float* wr = w_qkv + (long)c * 768;
        a0 += xc * wr[t];
        a1 += xc * wr[t + 256];
        a2 += xc * wr[t + 512];
    }
    int h = t >> 6, dd = t & 63;
    q[((b * H_ + h) * N_ + n) * DH_ + dd]  = a0 * 0.125f;      // dh^-0.5 pre-applied
    kT[((b * H_ + h) * DH_ + dd) * N_ + n] = a1;               // transposed for coalesced K3
    v[((b * H_ + h) * N_ + n) * DH_ + dd]  = a2;
    if (t < 8) {
        float acc = b_gate[t];
        for (int c = 0; c < DIM_; c++) acc += xs[c] * w_gate[c * 8 + t];
        float g = 1.0f / (1.0f + __expf(-acc));
        if (t < 4) og[(b * H_ + t) * N_ + n] = g;
        else       rg[(b * H_ + (t - 4)) * N_ + n] = g;
    }
}

// ---------- K2: position-bias MLP as fused MFMA GEMM ----------
// Tile = 128 pairs. 4 waves split N (32 output cols each). Weights (f16,
// transposed) live in REGISTERS as MFMA B-fragments: W1 32 VGPR, W2 32, wqk 16.
// h tile [128][136] f16 in LDS (pad 8 -> 2-way bank aliasing = free).
// LN between layers: quad butterfly partials -> LDS combine -> in-reg apply.
__global__ __launch_bounds__(256, 2) void eq_k2(
    const float* __restrict__ coors,
    const float* __restrict__ w0, const float* __restrict__ b0,
    const float* __restrict__ g0, const float* __restrict__ be0,
    const float* __restrict__ W1g, const float* __restrict__ b1,
    const float* __restrict__ g1, const float* __restrict__ be1,
    const float* __restrict__ W2g, const float* __restrict__ b2,
    const float* __restrict__ g2, const float* __restrict__ be2,
    const float* __restrict__ wqk, const float* __restrict__ bqk,
    _Float16* __restrict__ pout, float* __restrict__ qkpos) {

    __shared__ _Float16 hS[128 * 136];    // 34816 B (h tile / weight-staging)
    __shared__ float prt[128 * 4 * 2];    // per-row (sum,sumsq) per wave
    __shared__ float mi[128 * 2];         // per-row (mean, invstd)
    __shared__ float distS[128];
    __shared__ float prm[1280];           // w0,b0,g0,be0,b1,g1,be1,b2,g2,be2
    __shared__ _Float16 wqT[16 * 128];    // wqk^T padded to 16 rows

    const int t = threadIdx.x;
    const int lane = t & 63, wv = t >> 6;
    const int l15 = lane & 15, quad = lane >> 4;
    const int col0 = wv * 32 + l15, col1 = col0 + 16;

    for (int i2 = t; i2 < 128; i2 += 256) {
        prm[i2] = w0[i2]; prm[128 + i2] = b0[i2]; prm[256 + i2] = g0[i2]; prm[384 + i2] = be0[i2];
        prm[512 + i2] = b1[i2]; prm[640 + i2] = g1[i2]; prm[768 + i2] = be1[i2];
        prm[896 + i2] = b2[i2]; prm[1024 + i2] = g2[i2]; prm[1152 + i2] = be2[i2];
    }
    for (int i2 = t; i2 < 2048; i2 += 256) {
        int n = i2 >> 7, k = i2 & 127;
        wqT[i2] = (n < 4) ? (_Float16)wqk[k * 4 + n] : (_Float16)0.f;
    }
    for (int i2 = t; i2 < 16384; i2 += 256) {   // W1^T -> hS (f16)
        int k = i2 >> 7, n = i2 & 127;
        hS[n * 136 + k] = (_Float16)W1g[i2];
    }
    __syncthreads();
    v8h B1[2][4], B2[2][4], WQ[4];
    #pragma unroll
    for (int nt = 0; nt < 2; nt++)
        #pragma unroll
        for (int kt = 0; kt < 4; kt++) {
            int n = wv * 32 + nt * 16 + l15;
            B1[nt][kt] = *(const v8h*)&hS[n * 136 + kt * 32 + quad * 8];
        }
    #pragma unroll
    for (int kt = 0; kt < 4; kt++)
        WQ[kt] = *(const v8h*)&wqT[l15 * 128 + kt * 32 + quad * 8];
    const float bs1a = prm[512 + col0], bs1b = prm[512 + col1];
    const float gg1a = prm[640 + col0], gg1b = prm[640 + col1];
    const float bb1a = prm[768 + col0], bb1b = prm[768 + col1];
    const float bs2a = prm[896 + col0], bs2b = prm[896 + col1];
    const float gg2a = prm[1024 + col0], gg2b = prm[1024 + col1];
    const float bb2a = prm[1152 + col0], bb2b = prm[1152 + col1];
    const float bq = (l15 < 4) ? bqk[l15] : 0.f;
    __syncthreads();
    for (int i2 = t; i2 < 16384; i2 += 256) {   // W2^T -> hS (f16)
        int k = i2 >> 7, n = i2 & 127;
        hS[n * 136 + k] = (_Float16)W2g[i2];
    }
    __syncthreads();
    #pragma unroll
    for (int nt = 0; nt < 2; nt++)
        #pragma unroll
        for (int kt = 0; kt < 4; kt++) {
            int n = wv * 32 + nt * 16 + l15;
            B2[nt][kt] = *(const v8h*)&hS[n * 136 + kt * 32 + quad * 8];
        }
    __syncthreads();

    const int TILES = (B_ * N_ * N_) / 128;   // 2304
    for (int tile = blockIdx.x; tile < TILES; tile += gridDim.x) {
        const int P0 = tile * 128;
        const int bb = P0 / (N_ * N_);
        const int rr = P0 - bb * (N_ * N_);
        const int ii = rr / N_;
        const int j0 = rr - ii * N_;          // 128 | 384 so (bb, ii) fixed per tile
        if (t < 128) {
            float dx = coors[(bb * N_ + ii) * 3 + 0] - coors[(bb * N_ + j0 + t) * 3 + 0];
            float dy = coors[(bb * N_ + ii) * 3 + 1] - coors[(bb * N_ + j0 + t) * 3 + 1];
            float dz = coors[(bb * N_ + ii) * 3 + 2] - coors[(bb * N_ + j0 + t) * 3 + 2];
            distS[t] = sqrtf(dx * dx + dy * dy + dz * dz);
        }
        __syncthreads();
        {   // layer0: h0[c] = silu(ln(dist*w0[c]+b0[c])) — 2 threads/row
            const int row = t >> 1, cb = (t & 1) << 6;
            float dist = distS[row];
            float s = 0.f, sq = 0.f;
            for (int ci = 0; ci < 64; ci++) {
                float vx = dist * prm[cb + ci] + prm[128 + cb + ci];
                s += vx; sq += vx * vx;
            }
            s += __shfl_xor(s, 1); sq += __shfl_xor(sq, 1);
            float mean = s * (1.f / 128.f);
            float inv = rsqrtf(sq * (1.f / 128.f) - mean * mean + 1e-5f);
            _Float16* hp = &hS[row * 136 + cb];
            for (int c8 = 0; c8 < 64; c8 += 8) {
                v8h o;
                #pragma unroll
                for (int jj = 0; jj < 8; jj++) {
                    int c = cb + c8 + jj;
                    float vx = dist * prm[c] + prm[128 + c];
                    float y = (vx - mean) * inv * prm[256 + c] + prm[384 + c];
                    o[jj] = (_Float16)(y / (1.f + __expf(-y)));
                }
                *(v8h*)&hp[c8] = o;
            }
        }
        __syncthreads();

        #pragma unroll 1
        for (int L = 0; L < 2; L++) {
            const float bsA = L ? bs2a : bs1a, bsB = L ? bs2b : bs1b;
            const float gA  = L ? gg2a : gg1a, gB  = L ? gg2b : gg1b;
            const float bA  = L ? bb2a : bb1a, bB  = L ? bb2b : bb1b;
            v4f acc[8][2];
            #pragma unroll
            for (int mt = 0; mt < 8; mt++) {
                const _Float16* hr = &hS[(mt * 16 + l15) * 136 + quad * 8];
                v8h a0 = *(const v8h*)&hr[0];
                v8h a1 = *(const v8h*)&hr[32];
                v8h a2 = *(const v8h*)&hr[64];
                v8h a3 = *(const v8h*)&hr[96];
                #pragma unroll
                for (int nt = 0; nt < 2; nt++) {
                    float bi = nt ? bsB : bsA;
                    v4f c = {bi, bi, bi, bi};
                    if (L == 0) {
                        c = __builtin_amdgcn_mfma_f32_16x16x32_f16(a0, B1[nt][0], c, 0, 0, 0);
                        c = __builtin_amdgcn_mfma_f32_16x16x32_f16(a1, B1[nt][1], c, 0, 0, 0);
                        c = __builtin_amdgcn_mfma_f32_16x16x32_f16(a2, B1[nt][2], c, 0, 0, 0);
                        c = __builtin_amdgcn_mfma_f32_16x16x32_f16(a3, B1[nt][3], c, 0, 0, 0);
                    } else {
                        c = __builtin_amdgcn_mfma_f32_16x16x32_f16(a0, B2[nt][0], c, 0, 0, 0);
                        c = __builtin_amdgcn_mfma_f32_16x16x32_f16(a1, B2[nt][1], c, 0, 0, 0);
                        c = __builtin_amdgcn_mfma_f32_16x16x32_f16(a2, B2[nt][2], c, 0, 0, 0);
                        c = __builtin_amdgcn_mfma_f32_16x16x32_f16(a3, B2[nt][3], c, 0, 0, 0);
                    }
                    acc[mt][nt] = c;
                }
            }
            // LN: per-row partials over this wave's 32 cols (quad butterfly)
            #pragma unroll
            for (int mt = 0; mt < 8; mt++) {
                float s[4], sq[4];
                #pragma unroll
                for (int rg = 0; rg < 4; rg++) {
                    float v0 = acc[mt][0][rg], v1 = acc[mt][1][rg];
                    s[rg] = v0 + v1; sq[rg] = v0 * v0 + v1 * v1;
                }
                #pragma unroll
                for (int o = 1; o < 16; o <<= 1) {
                    #pragma unroll
                    for (int rg = 0; rg < 4; rg++) {
                        s[rg] += __shfl_xor(s[rg], o);
                        sq[rg] += __shfl_xor(sq[rg], o);
                    }
                }
                if (l15 == 0) {
                    #pragma unroll
                    for (int rg = 0; rg < 4; rg++) {
                        int row = mt * 16 + quad * 4 + rg;
                        *(float2*)&prt[(row * 4 + wv) * 2] = make_float2(s[rg], sq[rg]);
                    }
                }
            }
            __syncthreads();
            if (t < 128) {
                float s = 0.f, sq = 0.f;
                #pragma unroll
                for (int w2 = 0; w2 < 4; w2++) {
                    float2 pv = *(const float2*)&prt[(t * 4 + w2) * 2];
                    s += pv.x; sq += pv.y;
                }
                float mean = s * (1.f / 128.f);
                mi[t * 2] = mean;
                mi[t * 2 + 1] = rsqrtf(sq * (1.f / 128.f) - mean * mean + 1e-5f);
            }
            __syncthreads();
            #pragma unroll
            for (int mt = 0; mt < 8; mt++) {
                #pragma unroll
                for (int rg = 0; rg < 4; rg++) {
                    int row = mt * 16 + quad * 4 + rg;
                    float2 m2 = *(const float2*)&mi[row * 2];
                    float y0 = (acc[mt][0][rg] - m2.x) * m2.y * gA + bA;
                    float y1 = (acc[mt][1][rg] - m2.x) * m2.y * gB + bB;
                    y0 = y0 / (1.f + __expf(-y0));
                    y1 = y1 / (1.f + __expf(-y1));
                    hS[row * 136 + col0] = (_Float16)y0;
                    hS[row * 136 + col1] = (_Float16)y1;
                }
            }
            __syncthreads();
        }

        // p store: coalesced 16B per thread
        #pragma unroll
        for (int it = 0; it < 8; it++) {
            int Lx = it * 2048 + t * 8;
            int row = Lx >> 7, cc = Lx & 127;
            *(v8h*)&pout[(long)(P0 + row) * 128 + cc] = *(const v8h*)&hS[row * 136 + cc];
        }
        // qk_pos = p @ wqk + bqk via mini-MFMA (each wave: 2 m-tiles)
        #pragma unroll
        for (int m2 = 0; m2 < 2; m2++) {
            int mt = wv * 2 + m2;
            const _Float16* hr = &hS[(mt * 16 + l15) * 136 + quad * 8];
            v8h a0 = *(const v8h*)&hr[0];
            v8h a1 = *(const v8h*)&hr[32];
            v8h a2 = *(const v8h*)&hr[64];
            v8h a3 = *(const v8h*)&hr[96];
            v4f c = {0.f, 0.f, 0.f, 0.f};
            c = __builtin_amdgcn_mfma_f32_16x16x32_f16(a0, WQ[0], c, 0, 0, 0);
            c = __builtin_amdgcn_mfma_f32_16x16x32_f16(a1, WQ[1], c, 0, 0, 0);
            c = __builtin_amdgcn_mfma_f32_16x16x32_f16(a2, WQ[2], c, 0, 0, 0);
            c = __builtin_amdgcn_mfma_f32_16x16x32_f16(a3, WQ[3], c, 0, 0, 0);
            if (l15 < 4) {
                #pragma unroll
                for (int rg = 0; rg < 4; rg++) {
                    int row = mt * 16 + quad * 4 + rg;
                    qkpos[(long)(P0 + row) * 4 + l15] = c[rg] + bq;
                }
            }
        }
        __syncthreads();
    }
}

// ---------- K3: qk scores + edge MLP -> cmi / coor_pre / rel_sign ----------
__global__ __launch_bounds__(384) void eq_k3(
    const float* __restrict__ q, const float* __restrict__ kT,
    const float* __restrict__ edges, const float* __restrict__ qkpos,
    const float* __restrict__ w_e1, const float* __restrict__ w_e2,
    const float* __restrict__ w_c, const float* __restrict__ w_cg,
    const float* __restrict__ b_cg,
    float* __restrict__ score, float* __restrict__ coorpre, float* __restrict__ relsign) {
    int row = blockIdx.x;           // b*N + i
    int b = row / N_, i = row - b * N_;
    int j = threadIdx.x;
    __shared__ float qs[H_ * DH_];
    __shared__ float we1[20 * 40];
    __shared__ float we2[40 * 4];
    __shared__ float wcs[16], wcgs[16], bcgs[4];
    if (j < 256) qs[j] = q[((b * H_ + (j >> 6)) * N_ + i) * DH_ + (j & 63)];
    for (int idx = j; idx < 800; idx += 384) we1[idx] = w_e1[idx];
    if (j < 160) we2[j] = w_e2[j];
    if (j < 16) { wcs[j] = w_c[j]; wcgs[j] = w_cg[j]; }
    if (j < 4) bcgs[j] = b_cg[j];
    __syncthreads();

    long pair = ((long)(b * N_ + i)) * N_ + j;
    float in20[20];
    #pragma unroll
    for (int h = 0; h < H_; h++) {
        float acc = 0;
        const float* kp = kT + ((long)(b * H_ + h) * DH_) * N_ + j;
        #pragma unroll 8
        for (int d = 0; d < DH_; d++) acc += qs[h * DH_ + d] * kp[(long)d * N_];
        in20[h] = acc + qkpos[pair * 4 + h];
    }
    const float4* ep = (const float4*)(edges + pair * ED_);
    float4 e0 = ep[0], e1 = ep[1], e2 = ep[2], e3 = ep[3];
    in20[4] = e0.x;  in20[5] = e0.y;  in20[6] = e0.z;  in20[7] = e0.w;
    in20[8] = e1.x;  in20[9] = e1.y;  in20[10] = e1.z; in20[11] = e1.w;
    in20[12] = e2.x; in20[13] = e2.y; in20[14] = e2.z; in20[15] = e2.w;
    in20[16] = e3.x; in20[17] = e3.y; in20[18] = e3.z; in20[19] = e3.w;

    float c0 = 0, c1 = 0, c2 = 0, c3 = 0;
    for (int o = 0; o < 40; o++) {
        float a = 0;
        #pragma unroll
        for (int c = 0; c < 20; c++) a += in20[c] * we1[c * 40 + o];
        float gg = gelu_(a);
        c0 += gg * we2[o * 4 + 0]; c1 += gg * we2[o * 4 + 1];
        c2 += gg * we2[o * 4 + 2]; c3 += gg * we2[o * 4 + 3];
    }
    float cmi[4] = {c0, c1, c2, c3};
    float gc[4];
    #pragma unroll
    for (int h = 0; h < 4; h++) gc[h] = gelu_(cmi[h]);
    #pragma unroll
    for (int h = 0; h < 4; h++) {
        long idx = (((long)(b * H_ + h) * N_ + i)) * N_ + j;
        score[idx] = cmi[h];
        coorpre[idx] = gc[0] * wcs[0 * 4 + h] + gc[1] * wcs[1 * 4 + h]
                     + gc[2] * wcs[2 * 4 + h] + gc[3] * wcs[3 * 4 + h];
        relsign[idx] = cmi[0] * wcgs[0 * 4 + h] + cmi[1] * wcgs[1 * 4 + h]
                     + cmi[2] * wcgs[2 * 4 + h] + cmi[3] * wcgs[3 * 4 + h] + bcgs[h];
    }
}

// ---------- K4a: softmax over j + talking heads ----------
__global__ __launch_bounds__(384) void eq_k4a(
    const float* __restrict__ score, const float* __restrict__ w_th,
    float* __restrict__ attn) {
    int row = blockIdx.x;
    int b = row / N_, i = row - b * N_;
    int j = threadIdx.x;
    __shared__ float red[8];
    float s[4], e[4], il[4];
    #pragma unroll
    for (int g = 0; g < 4; g++)
        s[g] = score[(((long)(b * H_ + g) * N_ + i)) * N_ + j];
    for (int g = 0; g < 4; g++) {
        float m = block_reduce(s[g], true, red, 6);
        e[g] = __expf(s[g] - m);
        float l = block_reduce(e[g], false, red, 6);
        il[g] = 1.0f / l;
    }
    #pragma unroll
    for (int h = 0; h < 4; h++) {
        float o = 0;
        #pragma unroll
        for (int g = 0; g < 4; g++) o += w_th[h * 4 + g] * e[g] * il[g];
        attn[(((long)(b * H_ + h) * N_ + i)) * N_ + j] = o;
    }
}

// ---------- K4b: coordinate branch -> out1 ----------
__global__ __launch_bounds__(384) void eq_k4b(
    const float* __restrict__ coorpre, const float* __restrict__ relsign,
    const float* __restrict__ coors, const float* __restrict__ rg,
    const float* __restrict__ cscale, const float* __restrict__ ccomb,
    float* __restrict__ out1) {
    int row = blockIdx.x;
    int b = row / N_, i = row - b * N_;
    int j = threadIdx.x;
    __shared__ float red[8];
    float cw[4], rs[4];
    #pragma unroll
    for (int h = 0; h < 4; h++) {
        long idx = (((long)(b * H_ + h) * N_ + i)) * N_ + j;
        cw[h] = coorpre[idx];
        rs[h] = relsign[idx];
    }
    float dx = coors[(b * N_ + i) * 3 + 0] - coors[(b * N_ + j) * 3 + 0];
    float dy = coors[(b * N_ + i) * 3 + 1] - coors[(b * N_ + j) * 3 + 1];
    float dz = coors[(b * N_ + i) * 3 + 2] - coors[(b * N_ + j) * 3 + 2];
    float nrm = sqrtf(dx * dx + dy * dy + dz * dz);
    float sc = cscale[0] / fmaxf(nrm, 1e-8f);
    float rx = dx * sc, ry = dy * sc, rz = dz * sc;
    float ox = 0, oy = 0, oz = 0;
    for (int h = 0; h < 4; h++) {
        float m = block_reduce(cw[h], true, red, 6);
        float e = __expf(cw[h] - m);
        float l = block_reduce(e, false, red, 6);
        float w = e / l * rs[h];
        float sx = block_reduce(w * rx, false, red, 6);
        float sy = block_reduce(w * ry, false, red, 6);
        float sz = block_reduce(w * rz, false, red, 6);
        float f = ccomb[h] * rg[(b * H_ + h) * N_ + i];
        ox += f * sx; oy += f * sy; oz += f * sz;
    }
    if (j == 0) {
        out1[(b * N_ + i) * 3 + 0] = ox;
        out1[(b * N_ + i) * 3 + 1] = oy;
        out1[(b * N_ + i) * 3 + 2] = oz;
    }
}

// ---------- K5a: ap[b,h,i,c] = sum_j attn * p ----------
__global__ __launch_bounds__(128) void eq_k5a(
    const float* __restrict__ attn, const _Float16* __restrict__ p,
    float* __restrict__ ap) {
    int row = blockIdx.x;           // b*N + i
    int b = row / N_, i = row - b * N_;
    int t = threadIdx.x;            // channel c
    __shared__ float arow[4 * N_];
    for (int idx = t; idx < 4 * N_; idx += 128) {
        int g = idx / N_, j = idx - g * N_;
        arow[idx] = attn[(((long)(b * H_ + g) * N_ + i)) * N_ + j];
    }
    __syncthreads();
    float a0 = 0, a1 = 0, a2 = 0, a3 = 0;
    const _Float16* pp = p + (long)row * N_ * PD_ + t;
    #pragma unroll 4
    for (int j = 0; j < N_; j++) {
        float pv = (float)pp[(long)j * PD_];
        a0 += arow[j] * pv;
        a1 += arow[N_ + j] * pv;
        a2 += arow[2 * N_ + j] * pv;
        a3 += arow[3 * N_ + j] * pv;
    }
    ap[(((long)(b * H_ + 0) * N_ + i)) * PD_ + t] = a0;
    ap[(((long)(b * H_ + 1) * N_ + i)) * PD_ + t] = a1;
    ap[(((long)(b * H_ + 2) * N_ + i)) * PD_ + t] = a2;
    ap[(((long)(b * H_ + 3) * N_ + i)) * PD_ + t] = a3;
}

// ---------- K5b: node_out = attn@v + ap@w_vpos + S_h*b_vpos, gated ----------
__global__ __launch_bounds__(64) void eq_k5b(
    const float* __restrict__ attn, const float* __restrict__ v,
    const float* __restrict__ ap, const float* __restrict__ w_vpos,
    const float* __restrict__ b_vpos, const float* __restrict__ w_th,
    const float* __restrict__ og, float* __restrict__ node) {
    int blk = blockIdx.x;           // (b*H+h)*N + i
    int bh = blk / N_, i = blk - bh * N_;
    int b = bh / H_, h = bh - b * H_;
    int d = threadIdx.x;
    __shared__ float arow[N_];
    __shared__ float aprow[PD_];
    for (int idx = d; idx < N_; idx += 64) arow[idx] = attn[(long)blk * N_ + idx];
    for (int idx = d; idx < PD_; idx += 64) aprow[idx] = ap[(long)blk * PD_ + idx];
    __syncthreads();
    float acc = 0;
    const float* vp = v + ((long)(b * H_ + h) * N_) * DH_ + d;
    #pragma unroll 8
    for (int j = 0; j < N_; j++) acc += arow[j] * vp[(long)j * DH_];
    float accp = 0;
    const float* wv = w_vpos + h * DH_ + d;
    #pragma unroll 8
    for (int c = 0; c < PD_; c++) accp += aprow[c] * wv[(long)c * (H_ * DH_)];
    float Sh = w_th[h * 4 + 0] + w_th[h * 4 + 1] + w_th[h * 4 + 2] + w_th[h * 4 + 3];
    float out = (acc + accp + Sh * b_vpos[h * DH_ + d]) * og[(b * H_ + h) * N_ + i];
    node[((long)(b * N_ + i) * H_ + h) * DH_ + d] = out;
}

// ---------- K6: final projection ----------
__global__ __launch_bounds__(256) void eq_k6(
    const float* __restrict__ node, const float* __restrict__ w_out,
    const float* __restrict__ b_out, float* __restrict__ out0) {
    int row = blockIdx.x;           // b*N + i
    int t = threadIdx.x;
    __shared__ float xs[256];
    xs[t] = node[(long)row * 256 + t];
    __syncthreads();
    float acc = b_out[t];
    for (int c = 0; c < 256; c++) acc += xs[c] * w_out[(long)c * 256 + t];
    out0[(long)row * 256 + t] = acc;
}

extern "C" void kernel_launch(void* const* d_in, const int* in_sizes, int n_in,
                              void* d_out, int out_size, void* d_ws, size_t ws_size,
                              hipStream_t stream) {
    (void)in_sizes; (void)n_in; (void)out_size; (void)ws_size;
    const float* feats   = (const float*)d_in[0];
    const float* coors   = (const float*)d_in[1];
    const float* edges   = (const float*)d_in[2];
    const float* gamma   = (const float*)d_in[3];
    const float* w_qkv   = (const float*)d_in[4];
    const float* w_gate  = (const float*)d_in[5];
    const float* b_gate  = (const float*)d_in[6];
    const float* w_th    = (const float*)d_in[7];
    const float* w_e1    = (const float*)d_in[8];
    const float* w_e2    = (const float*)d_in[9];
    const float* w_c     = (const float*)d_in[10];
    const float* w_cg    = (const float*)d_in[11];
    const float* b_cg    = (const float*)d_in[12];
    const float* cscale  = (const float*)d_in[13];
    const float* ccomb   = (const float*)d_in[14];
    const float* pb_w0   = (const float*)d_in[15];
    const float* pb_b0   = (const float*)d_in[16];
    const float* pb_g0   = (const float*)d_in[17];
    const float* pb_be0  = (const float*)d_in[18];
    const float* pb_w1   = (const float*)d_in[19];
    const float* pb_b1   = (const float*)d_in[20];
    const float* pb_g1   = (const float*)d_in[21];
    const float* pb_be1  = (const float*)d_in[22];
    const float* pb_w2   = (const float*)d_in[23];
    const float* pb_b2   = (const float*)d_in[24];
    const float* pb_g2   = (const float*)d_in[25];
    const float* pb_be2  = (const float*)d_in[26];
    const float* w_qkpos = (const float*)d_in[27];
    const float* b_qkpos = (const float*)d_in[28];
    const float* w_vpos  = (const float*)d_in[29];
    const float* b_vpos  = (const float*)d_in[30];
    const float* w_out   = (const float*)d_in[31];
    const float* b_out   = (const float*)d_in[32];

    // workspace carve (floats)
    float* wsf    = (float*)d_ws;
    float* q      = wsf;                    // 196608
    float* kT     = q      + 196608;        // 196608
    float* v      = kT     + 196608;        // 196608
    float* og     = v      + 196608;        // 3072
    float* rg     = og     + 3072;          // 3072
    float* qkpos  = rg     + 3072;          // 1179648 (b,i,j,h)
    float* score  = qkpos  + 1179648;       // 1179648 (b,h,i,j)
    float* coorpre= score  + 1179648;       // 1179648
    float* relsign= coorpre+ 1179648;       // 1179648
    float* attn   = relsign+ 1179648;       // 1179648
    float* ap     = attn   + 1179648;       // 393216
    float* node   = ap     + 393216;        // 196608
    _Float16* pbuf = (_Float16*)(node + 196608);  // 37748736 f16

    float* out0 = (float*)d_out;
    float* out1 = out0 + (long)B_ * N_ * DIM_;

    eq_k1<<<B_ * N_, 256, 0, stream>>>(feats, gamma, w_qkv, w_gate, b_gate, q, kT, v, og, rg);
    eq_k2<<<512, 256, 0, stream>>>(coors, pb_w0, pb_b0, pb_g0, pb_be0,
                                   pb_w1, pb_b1, pb_g1, pb_be1,
                                   pb_w2, pb_b2, pb_g2, pb_be2,
                                   w_qkpos, b_qkpos, pbuf, qkpos);
    eq_k3<<<B_ * N_, 384, 0, stream>>>(q, kT, edges, qkpos, w_e1, w_e2, w_c, w_cg, b_cg,
                                       score, coorpre, relsign);
    eq_k4a<<<B_ * N_, 384, 0, stream>>>(score, w_th, attn);
    eq_k4b<<<B_ * N_, 384, 0, stream>>>(coorpre, relsign, coors, rg, cscale, ccomb, out1);
    eq_k5a<<<B_ * N_, 128, 0, stream>>>(attn, pbuf, ap);
    eq_k5b<<<B_ * H_ * N_, 64, 0, stream>>>(attn, v, ap, w_vpos, b_vpos, w_th, og, node);
    eq_k6<<<B_ * N_, 256, 0, stream>>>(node, w_out, b_out, out0);
}